// Round 7
// baseline (679.870 us; speedup 1.0000x reference)
//
#include <hip/hip_runtime.h>
#include <hip/hip_fp16.h>
#include <math.h>

#define NB1 10000
#define NB2 10000
#define DD  128
#define NV  4
#define B1P 10016            // desc1 rows padded to 32
#define B1R (B1P * NV)       // 40064 A-rows (313 * 128)
#define NB2P 10112           // 79 * 128 B rows
#define NB2A (NB2P + 128)    // +128 slack rows for the dead tail prefetch
#define NJT 79               // j-tiles of 128
#define MB  128              // A-rows per block
#define BN  128
#define NCHUNK 4
#define SROWS 16
#define SCALE 64.0f          // descriptor pre-scale; acc = 4096*dot, epilogue applies -2/4096

typedef _Float16 f16x8 __attribute__((ext_vector_type(8)));
typedef __attribute__((ext_vector_type(16))) float f32x16;

__device__ __forceinline__ void gload_lds16(const void* g, void* l) {
    __builtin_amdgcn_global_load_lds(
        (const __attribute__((address_space(1))) void*)g,
        (__attribute__((address_space(3))) void*)l, 16, 0, 0);
}
__device__ __forceinline__ f32x16 mfma16(f16x8 a, f16x8 b, f32x16 c) {
    return __builtin_amdgcn_mfma_f32_32x32x16_f16(a, b, c, 0, 0, 0);
}
// encode x*SCALE as f16 hi/lo bit patterns
__device__ __forceinline__ void enc(float x, unsigned short* hb, unsigned short* lb) {
    float xs = SCALE * x;
    __half hh = __float2half_rn(xs);
    __half hl = __float2half_rn(xs - __half2float(hh));
    *hb = __half_as_ushort(hh);
    *lb = __half_as_ushort(hl);
}

// ---------------- prep (unchanged from passing R5 kernel) ----------------

__global__ void gt_kernel(const float* __restrict__ G, float* __restrict__ GT) {
    int idx = blockIdx.x * 256 + threadIdx.x;
    if (idx < DD * DD) {
        int c = idx / DD, f = idx % DD;
        GT[idx] = G[f * DD + c];
    }
}

__global__ void prep1_kernel(const float* __restrict__ desc1,
                             unsigned short* __restrict__ A2, float* __restrict__ F0,
                             float* __restrict__ n1) {
    int i = blockIdx.x;           // 0..B1P-1
    int t = threadIdx.x;          // 128
    float x = (i < NB1) ? desc1[i * DD + t] : 0.f;
    F0[(size_t)i * DD + t] = x;
    unsigned short hb, lb;
    enc(x, &hb, &lb);
    size_t base = (size_t)(i * NV) * 256;
    A2[base + t] = hb;
    A2[base + 128 + t] = lb;
    float s = x * x;
    for (int off = 32; off; off >>= 1) s += __shfl_down(s, off);
    __shared__ float p[2];
    if ((t & 63) == 0) p[t >> 6] = s;
    __syncthreads();
    if (t == 0) n1[i * NV] = p[0] + p[1];
}

__global__ void prep2_kernel(const float* __restrict__ desc2,
                             unsigned short* __restrict__ B2, float* __restrict__ n2) {
    int j = blockIdx.x;           // 0..NB2P-1
    int t = threadIdx.x;          // 128
    float x = (j < NB2) ? desc2[j * DD + t] : 0.f;
    unsigned short hb, lb;
    enc(x, &hb, &lb);
    size_t base = (size_t)j * 256;
    B2[base + t] = hb;
    B2[base + 128 + t] = lb;
    float s = x * x;
    for (int off = 32; off; off >>= 1) s += __shfl_down(s, off);
    __shared__ float p[2];
    if ((t & 63) == 0) p[t >> 6] = s;
    __syncthreads();
    if (t == 0) n2[j] = (j < NB2) ? (p[0] + p[1]) : 1e30f;
}

// in-place steering (each block reads only its own 16 rows into LDS first)
__global__ void steer_kernel(float* __restrict__ F, unsigned short* __restrict__ A2,
                             const float* __restrict__ GT, float* __restrict__ n1, int k) {
    __shared__ float src[SROWS][DD];
    int i0 = blockIdx.x * SROWS;
    int t = threadIdx.x;          // 128
    for (int r = 0; r < SROWS; ++r)
        src[r][t] = F[(size_t)(i0 + r) * DD + t];
    __syncthreads();
    float out[SROWS];
#pragma unroll
    for (int r = 0; r < SROWS; ++r) out[r] = 0.f;
    for (int c = 0; c < DD; ++c) {
        float g = GT[c * DD + t];
#pragma unroll
        for (int r = 0; r < SROWS; ++r) out[r] = fmaf(src[r][c], g, out[r]);
    }
    __shared__ float p2[SROWS][2];
    for (int r = 0; r < SROWS; ++r) {
        F[(size_t)(i0 + r) * DD + t] = out[r];
        unsigned short hb, lb;
        enc(out[r], &hb, &lb);
        size_t base = (size_t)((i0 + r) * NV + k) * 256;
        A2[base + t] = hb;
        A2[base + 128 + t] = lb;
        float s = out[r] * out[r];
        for (int off = 32; off; off >>= 1) s += __shfl_down(s, off);
        if ((t & 63) == 0) p2[r][t >> 6] = s;
    }
    __syncthreads();
    if (t < SROWS) n1[(i0 + t) * NV + k] = p2[t][0] + p2[t][1];
}

// ---------------- fused MFMA match kernel (B-in-regs pipelined) ----------------
// A persistent in LDS (64KB, fragment-ready 1KB chunks). B fragments loaded
// global->VGPR one K-step ahead (ping-pong bE/bO). No per-step barriers.
// st order: st0,1 = Ahi*Bhi ; st2,3 = Alo*Bhi ; st4,5 = Ahi*Blo.
//   aks(st) = {0,1,2,3,0,1}[st], segB = (st>=4)?128:0, kc = (st&1)*64.

#define PREFETCH(dst, j0v, ST)                                                   \
    {                                                                            \
        const int segB_ = ((ST) >= 4) ? 128 : 0;                                 \
        const int kc_ = ((ST) & 1) * 64;                                         \
        _Pragma("unroll")                                                        \
        for (int k16_ = 0; k16_ < 4; ++k16_) {                                   \
            _Pragma("unroll")                                                    \
            for (int b_ = 0; b_ < 2; ++b_) {                                     \
                int jrow_ = (j0v) + (wn * 2 + b_) * 32 + c5;                     \
                dst[k16_ * 2 + b_] = *(const f16x8*)(                            \
                    B2 + (size_t)jrow_ * 256 + segB_ + kc_ + k16_ * 16 + h * 8); \
            }                                                                    \
        }                                                                        \
    }

#define COMPUTE(buf, AKS)                                                        \
    {                                                                            \
        _Pragma("unroll")                                                        \
        for (int k16_ = 0; k16_ < 4; ++k16_) {                                   \
            f16x8 a0_ = *(const f16x8*)(LDS + ((((AKS) * 4 + k16_) * 4 + wm * 2 + 0) * 1024) + l * 16); \
            f16x8 a1_ = *(const f16x8*)(LDS + ((((AKS) * 4 + k16_) * 4 + wm * 2 + 1) * 1024) + l * 16); \
            acc[0][0] = mfma16(a0_, buf[k16_ * 2 + 0], acc[0][0]);               \
            acc[0][1] = mfma16(a0_, buf[k16_ * 2 + 1], acc[0][1]);               \
            acc[1][0] = mfma16(a1_, buf[k16_ * 2 + 0], acc[1][0]);               \
            acc[1][1] = mfma16(a1_, buf[k16_ * 2 + 1], acc[1][1]);               \
        }                                                                        \
    }

__global__ __launch_bounds__(256) void match_kernel(
    const unsigned short* __restrict__ A2, const unsigned short* __restrict__ B2,
    const float* __restrict__ n1, const float* __restrict__ n2,
    float* __restrict__ pb, int* __restrict__ pj) {
    __shared__ __align__(16) char LDS[64 * 1024];   // A only
    const int t = threadIdx.x;
    const int l = t & 63, w = t >> 6;
    const int wm = w >> 1, wn = w & 1;
    const int c5 = l & 31, h = l >> 5;
    const int bi = blockIdx.x, ch = blockIdx.y;
    const int R0 = bi * MB;

    // ---- stage A once: 64 chunks, 16 per wave ----
#pragma unroll
    for (int q = 0; q < 16; ++q) {
        int chunk = w * 16 + q;
        int aks = chunk >> 4, k16 = (chunk >> 2) & 3, mf = chunk & 3;
        int row = R0 + mf * 32 + c5;
        int col = aks * 64 + k16 * 16 + h * 8;
        gload_lds16(A2 + (size_t)row * 256 + col, LDS + chunk * 1024 + l * 16);
    }
    __syncthreads();   // drains A-stage vmcnt; the only barrier in the kernel

    float4 n1r[2][4];
#pragma unroll
    for (int a = 0; a < 2; ++a)
#pragma unroll
        for (int rq = 0; rq < 4; ++rq)
            n1r[a][rq] = *(const float4*)&n1[R0 + (wm * 2 + a) * 32 + 8 * rq + 4 * h];

    float best[2][4];
    int bj[2][4];
#pragma unroll
    for (int a = 0; a < 2; ++a)
#pragma unroll
        for (int rq = 0; rq < 4; ++rq) { best[a][rq] = 3.4e38f; bj[a][rq] = 0; }

    const int jt0 = (ch * NJT) / NCHUNK;
    const int jt1 = ((ch + 1) * NJT) / NCHUNK;

    f16x8 bE[8], bO[8];
    PREFETCH(bE, jt0 * BN, 0);

    for (int jt = jt0; jt < jt1; ++jt) {
        const int j0 = jt * BN;
        f32x16 acc[2][2];
#pragma unroll
        for (int a = 0; a < 2; ++a)
#pragma unroll
            for (int b = 0; b < 2; ++b)
#pragma unroll
                for (int e = 0; e < 16; ++e) acc[a][b][e] = 0.f;

        PREFETCH(bO, j0, 1);        COMPUTE(bE, 0);   // st=0
        PREFETCH(bE, j0, 2);        COMPUTE(bO, 1);   // st=1
        PREFETCH(bO, j0, 3);        COMPUTE(bE, 2);   // st=2
        PREFETCH(bE, j0, 4);        COMPUTE(bO, 3);   // st=3
        PREFETCH(bO, j0, 5);        COMPUTE(bE, 0);   // st=4
        PREFETCH(bE, j0 + BN, 0);   COMPUTE(bO, 1);   // st=5 (+ next-tile prefetch; slack rows cover tail)

        // epilogue: e_m = n1_m - 2*dot (dot = acc/4096) ; min over versions ; + n2 ; argmin
        float nn0 = n2[j0 + wn * 64 + c5];
        float nn1 = n2[j0 + wn * 64 + 32 + c5];
#pragma unroll
        for (int a = 0; a < 2; ++a)
#pragma unroll
            for (int b = 0; b < 2; ++b) {
                float nn = b ? nn1 : nn0;
                int j = j0 + wn * 64 + b * 32 + c5;
#pragma unroll
                for (int rq = 0; rq < 4; ++rq) {
                    float e0 = fmaf(-0.00048828125f, acc[a][b][4 * rq + 0], n1r[a][rq].x);
                    float e1 = fmaf(-0.00048828125f, acc[a][b][4 * rq + 1], n1r[a][rq].y);
                    float e2 = fmaf(-0.00048828125f, acc[a][b][4 * rq + 2], n1r[a][rq].z);
                    float e3 = fmaf(-0.00048828125f, acc[a][b][4 * rq + 3], n1r[a][rq].w);
                    float d = fminf(fminf(e0, e1), fminf(e2, e3)) + nn;
                    if (d < best[a][rq]) { best[a][rq] = d; bj[a][rq] = j; }
                }
            }
    }

    // reduce across the 32 column-lanes
#pragma unroll
    for (int off = 1; off < 32; off <<= 1) {
#pragma unroll
        for (int a = 0; a < 2; ++a)
#pragma unroll
            for (int rq = 0; rq < 4; ++rq) {
                float ov = __shfl_xor(best[a][rq], off);
                int oj = __shfl_xor(bj[a][rq], off);
                if (ov < best[a][rq] || (ov == best[a][rq] && oj < bj[a][rq])) {
                    best[a][rq] = ov; bj[a][rq] = oj;
                }
            }
    }
    if (c5 == 0) {
        int slot = ch * 2 + wn;
#pragma unroll
        for (int a = 0; a < 2; ++a)
#pragma unroll
            for (int rq = 0; rq < 4; ++rq) {
                int i = bi * 32 + (wm * 2 + a) * 8 + 2 * rq + h;
                pb[slot * B1P + i] = best[a][rq];
                pj[slot * B1P + i] = bj[a][rq];
            }
    }
}

__global__ void final_kernel(const float* __restrict__ pb, const int* __restrict__ pj,
                             float* __restrict__ out) {
    int i = blockIdx.x * 256 + threadIdx.x;
    if (i < NB1) {
        float bv = 3.4e38f;
        int bj = 0;
#pragma unroll
        for (int s = 0; s < 2 * NCHUNK; ++s) {
            float v = pb[s * B1P + i];
            int j = pj[s * B1P + i];
            if (v < bv || (v == bv && j < bj)) { bv = v; bj = j; }
        }
        out[i] = sqrtf(fmaxf(bv, 0.f));
        out[NB1 + 2 * i] = (float)i;
        out[NB1 + 2 * i + 1] = (float)bj;
    }
}

// ---------------- launch ----------------

extern "C" void kernel_launch(void* const* d_in, const int* in_sizes, int n_in,
                              void* d_out, int out_size, void* d_ws, size_t ws_size,
                              hipStream_t stream) {
    const float* desc1 = (const float*)d_in[0];
    const float* desc2 = (const float*)d_in[1];
    const float* G     = (const float*)d_in[2];

    unsigned short* A2 = (unsigned short*)d_ws;              // B1R*256 ushort
    unsigned short* B2 = A2 + (size_t)B1R * 256;             // NB2A*256 ushort (incl slack)
    float* F0 = (float*)(B2 + (size_t)NB2A * 256);           // B1P*DD fp32 chain (in-place)
    float* GT = F0 + (size_t)B1P * DD;                       // DD*DD
    float* n1 = GT + DD * DD;                                // B1R
    float* n2 = n1 + B1R;                                    // NB2P
    float* pb = n2 + NB2P;                                   // 2*NCHUNK*B1P
    int*   pj = (int*)(pb + 2 * NCHUNK * B1P);               // 2*NCHUNK*B1P
    float* out = (float*)d_out;

    hipLaunchKernelGGL(gt_kernel, dim3((DD * DD + 255) / 256), dim3(256), 0, stream, G, GT);
    hipLaunchKernelGGL(prep1_kernel, dim3(B1P), dim3(DD), 0, stream, desc1, A2, F0, n1);
    hipLaunchKernelGGL(prep2_kernel, dim3(NB2P), dim3(DD), 0, stream, desc2, B2, n2);
    for (int k = 1; k < NV; ++k)
        hipLaunchKernelGGL(steer_kernel, dim3(B1P / SROWS), dim3(DD), 0, stream,
                           F0, A2, GT, n1, k);
    hipLaunchKernelGGL(match_kernel, dim3(B1R / MB, NCHUNK), dim3(256), 0, stream,
                       A2, B2, n1, n2, pb, pj);
    hipLaunchKernelGGL(final_kernel, dim3((NB1 + 255) / 256), dim3(256), 0, stream,
                       pb, pj, out);
}

// Round 8
// 443.512 us; speedup vs baseline: 1.5329x; 1.5329x over previous
//
#include <hip/hip_runtime.h>
#include <hip/hip_fp16.h>
#include <math.h>

#define NB1 10000
#define NB2 10000
#define DD  128
#define NV  4
#define B1P 10016            // desc1 rows padded to 32
#define B1R (B1P * NV)       // 40064 A-rows = 1252 row-groups of 32
#define NB2P 10112           // 316 row-groups of 32
#define NB2G 320             // B2c groups incl 4 slack (dead tail prefetch)
#define NJT 79               // j-tiles of 128
#define MB  128
#define BN  128
#define NCHUNK 4
#define SROWS 16
#define SCALE 64.0f          // pre-scale; acc = 4096*dot, epilogue applies -2/4096

typedef _Float16 f16x8 __attribute__((ext_vector_type(8)));
typedef __attribute__((ext_vector_type(16))) float f32x16;

__device__ __forceinline__ void gload_lds16(const void* g, void* l) {
    __builtin_amdgcn_global_load_lds(
        (const __attribute__((address_space(1))) void*)g,
        (__attribute__((address_space(3))) void*)l, 16, 0, 0);
}
__device__ __forceinline__ f32x16 mfma16(f16x8 a, f16x8 b, f32x16 c) {
    return __builtin_amdgcn_mfma_f32_32x32x16_f16(a, b, c, 0, 0, 0);
}
__device__ __forceinline__ void enc(float x, unsigned short* hb, unsigned short* lb) {
    float xs = SCALE * x;
    __half hh = __float2half_rn(xs);
    __half hl = __float2half_rn(xs - __half2float(hh));
    *hb = __half_as_ushort(hh);
    *lb = __half_as_ushort(hl);
}
// chunk-major map (ushort index): chunk = (rowgroup, col/16) of 512 ushort;
// within chunk: lane = (row&31) + bit3(col)*32, elem = col&7.  Lane-linear = MFMA fragment order.
__device__ __forceinline__ size_t cmap(int row, int col) {
    return ((size_t)(row >> 5) * 16 + (col >> 4)) * 512
         + (size_t)((row & 31) + (((col >> 3) & 1) << 5)) * 8 + (col & 7);
}

// ---------------- prep ----------------

__global__ void gt_kernel(const float* __restrict__ G, float* __restrict__ GT) {
    int idx = blockIdx.x * 256 + threadIdx.x;
    if (idx < DD * DD) {
        int c = idx / DD, f = idx % DD;
        GT[idx] = G[f * DD + c];
    }
}

__global__ void prep1_kernel(const float* __restrict__ desc1,
                             unsigned short* __restrict__ A2c, float* __restrict__ F0,
                             float* __restrict__ n1) {
    int i = blockIdx.x;           // 0..B1P-1
    int t = threadIdx.x;          // 128
    float x = (i < NB1) ? desc1[i * DD + t] : 0.f;
    F0[(size_t)i * DD + t] = x;
    unsigned short hb, lb;
    enc(x, &hb, &lb);
    int ar = i * NV;
    A2c[cmap(ar, t)] = hb;
    A2c[cmap(ar, 128 + t)] = lb;
    float s = x * x;
    for (int off = 32; off; off >>= 1) s += __shfl_down(s, off);
    __shared__ float p[2];
    if ((t & 63) == 0) p[t >> 6] = s;
    __syncthreads();
    if (t == 0) n1[i * NV] = p[0] + p[1];
}

__global__ void prep2_kernel(const float* __restrict__ desc2,
                             unsigned short* __restrict__ B2c, float* __restrict__ n2) {
    int j = blockIdx.x;           // 0..NB2P-1
    int t = threadIdx.x;          // 128
    float x = (j < NB2) ? desc2[j * DD + t] : 0.f;
    unsigned short hb, lb;
    enc(x, &hb, &lb);
    B2c[cmap(j, t)] = hb;
    B2c[cmap(j, 128 + t)] = lb;
    float s = x * x;
    for (int off = 32; off; off >>= 1) s += __shfl_down(s, off);
    __shared__ float p[2];
    if ((t & 63) == 0) p[t >> 6] = s;
    __syncthreads();
    if (t == 0) n2[j] = (j < NB2) ? (p[0] + p[1]) : 1e30f;
}

// in-place steering chain (each block reads only its own 16 rows first)
__global__ void steer_kernel(float* __restrict__ F, unsigned short* __restrict__ A2c,
                             const float* __restrict__ GT, float* __restrict__ n1, int k) {
    __shared__ float src[SROWS][DD];
    int i0 = blockIdx.x * SROWS;
    int t = threadIdx.x;          // 128
    for (int r = 0; r < SROWS; ++r)
        src[r][t] = F[(size_t)(i0 + r) * DD + t];
    __syncthreads();
    float out[SROWS];
#pragma unroll
    for (int r = 0; r < SROWS; ++r) out[r] = 0.f;
    for (int c = 0; c < DD; ++c) {
        float g = GT[c * DD + t];
#pragma unroll
        for (int r = 0; r < SROWS; ++r) out[r] = fmaf(src[r][c], g, out[r]);
    }
    __shared__ float p2[SROWS][2];
    for (int r = 0; r < SROWS; ++r) {
        F[(size_t)(i0 + r) * DD + t] = out[r];
        unsigned short hb, lb;
        enc(out[r], &hb, &lb);
        int ar = (i0 + r) * NV + k;
        A2c[cmap(ar, t)] = hb;
        A2c[cmap(ar, 128 + t)] = lb;
        float s = out[r] * out[r];
        for (int off = 32; off; off >>= 1) s += __shfl_down(s, off);
        if ((t & 63) == 0) p2[r][t >> 6] = s;
    }
    __syncthreads();
    if (t < SROWS) n1[(i0 + t) * NV + k] = p2[t][0] + p2[t][1];
}

// ---------------- fused MFMA match kernel ----------------
// A fragments in VGPRs (128), B in LDS ping-pong 2x8KB, 8 phases/j-tile.
// Phase: stage next 8KB -> other buf; ds_read+MFMA from current buf; barrier.
// B-groups: g0=Bhi-kc0 x{aks0,aks2}, g1=Bhi-kc1 x{aks1,aks3}, g2=Blo-kc0 x{aks0}, g3=Blo-kc1 x{aks1}.

#define STAGEPH(BSEL, J0V, C16B, HALF)                                            \
    {                                                                             \
        _Pragma("unroll")                                                         \
        for (int c_ = 0; c_ < 2; ++c_) {                                          \
            int chunk_ = w * 2 + c_;                                              \
            int k16h_ = chunk_ >> 2, nf_ = chunk_ & 3;                            \
            size_t gc_ = (size_t)(((J0V) >> 5) + nf_) * 16 + (C16B) + (HALF) * 2 + k16h_; \
            gload_lds16((const char*)B2c + gc_ * 1024 + l * 16,                   \
                        LDSB + (BSEL) * 8192 + chunk_ * 1024 + l * 16);           \
        }                                                                         \
    }

#define COMP2(BSEL, HALF, AK0, AK1)                                               \
    {                                                                             \
        _Pragma("unroll")                                                         \
        for (int kh_ = 0; kh_ < 2; ++kh_) {                                       \
            f16x8 b0_ = *(const f16x8*)(LDSB + (BSEL) * 8192 + (kh_ * 4 + wn * 2 + 0) * 1024 + l * 16); \
            f16x8 b1_ = *(const f16x8*)(LDSB + (BSEL) * 8192 + (kh_ * 4 + wn * 2 + 1) * 1024 + l * 16); \
            acc[0][0] = mfma16(Areg[0][AK0][(HALF) * 2 + kh_], b0_, acc[0][0]);   \
            acc[0][1] = mfma16(Areg[0][AK0][(HALF) * 2 + kh_], b1_, acc[0][1]);   \
            acc[1][0] = mfma16(Areg[1][AK0][(HALF) * 2 + kh_], b0_, acc[1][0]);   \
            acc[1][1] = mfma16(Areg[1][AK0][(HALF) * 2 + kh_], b1_, acc[1][1]);   \
            acc[0][0] = mfma16(Areg[0][AK1][(HALF) * 2 + kh_], b0_, acc[0][0]);   \
            acc[0][1] = mfma16(Areg[0][AK1][(HALF) * 2 + kh_], b1_, acc[0][1]);   \
            acc[1][0] = mfma16(Areg[1][AK1][(HALF) * 2 + kh_], b0_, acc[1][0]);   \
            acc[1][1] = mfma16(Areg[1][AK1][(HALF) * 2 + kh_], b1_, acc[1][1]);   \
        }                                                                         \
    }

#define COMP1(BSEL, HALF, AK0)                                                    \
    {                                                                             \
        _Pragma("unroll")                                                         \
        for (int kh_ = 0; kh_ < 2; ++kh_) {                                       \
            f16x8 b0_ = *(const f16x8*)(LDSB + (BSEL) * 8192 + (kh_ * 4 + wn * 2 + 0) * 1024 + l * 16); \
            f16x8 b1_ = *(const f16x8*)(LDSB + (BSEL) * 8192 + (kh_ * 4 + wn * 2 + 1) * 1024 + l * 16); \
            acc[0][0] = mfma16(Areg[0][AK0][(HALF) * 2 + kh_], b0_, acc[0][0]);   \
            acc[0][1] = mfma16(Areg[0][AK0][(HALF) * 2 + kh_], b1_, acc[0][1]);   \
            acc[1][0] = mfma16(Areg[1][AK0][(HALF) * 2 + kh_], b0_, acc[1][0]);   \
            acc[1][1] = mfma16(Areg[1][AK0][(HALF) * 2 + kh_], b1_, acc[1][1]);   \
        }                                                                         \
    }

__global__ __launch_bounds__(256, 2) void match_kernel(
    const unsigned short* __restrict__ A2c, const unsigned short* __restrict__ B2c,
    const float* __restrict__ n1, const float* __restrict__ n2,
    float* __restrict__ pb, int* __restrict__ pj) {
    __shared__ __align__(16) char LDSB[16384];   // B ping-pong 2x8KB
    __shared__ float LDSn1[128];
    const int t = threadIdx.x;
    const int l = t & 63, w = t >> 6;
    const int wm = w >> 1, wn = w & 1;
    const int c5 = l & 31, h = l >> 5;
    const int bi = blockIdx.x, ch = blockIdx.y;
    const int R0 = bi * MB;

    // ---- A fragments -> registers (32 coalesced 1KB wave-loads) ----
    f16x8 Areg[2][4][4];
#pragma unroll
    for (int a = 0; a < 2; ++a)
#pragma unroll
        for (int aks = 0; aks < 4; ++aks)
#pragma unroll
            for (int k16 = 0; k16 < 4; ++k16) {
                size_t g = (size_t)(bi * 4 + wm * 2 + a);
                Areg[a][aks][k16] = *(const f16x8*)(
                    (const char*)A2c + (g * 16 + aks * 4 + k16) * 1024 + l * 16);
            }

    const int jt0 = (ch * NJT) / NCHUNK;
    const int jt1 = ((ch + 1) * NJT) / NCHUNK;

    // prologue: stage (jt0, g0, half0) into buf0; n1 -> LDS
    STAGEPH(0, jt0 * BN, 0, 0);
    if (t < 128) LDSn1[t] = n1[R0 + t];
    __syncthreads();

    float best[2][4];
    int bj[2][4];
#pragma unroll
    for (int a = 0; a < 2; ++a)
#pragma unroll
        for (int rq = 0; rq < 4; ++rq) { best[a][rq] = 3.4e38f; bj[a][rq] = 0; }

    for (int jt = jt0; jt < jt1; ++jt) {
        const int j0 = jt * BN;
        f32x16 acc[2][2];
#pragma unroll
        for (int a = 0; a < 2; ++a)
#pragma unroll
            for (int b = 0; b < 2; ++b)
#pragma unroll
                for (int e = 0; e < 16; ++e) acc[a][b][e] = 0.f;

        STAGEPH(1, j0, 0, 1);       COMP2(0, 0, 0, 2); __syncthreads();   // q0: g0.h0
        STAGEPH(0, j0, 4, 0);       COMP2(1, 1, 0, 2); __syncthreads();   // q1: g0.h1
        STAGEPH(1, j0, 4, 1);       COMP2(0, 0, 1, 3); __syncthreads();   // q2: g1.h0
        STAGEPH(0, j0, 8, 0);       COMP2(1, 1, 1, 3); __syncthreads();   // q3: g1.h1
        STAGEPH(1, j0, 8, 1);       COMP1(0, 0, 0);    __syncthreads();   // q4: g2.h0
        STAGEPH(0, j0, 12, 0);      COMP1(1, 1, 0);    __syncthreads();   // q5: g2.h1
        STAGEPH(1, j0, 12, 1);      COMP1(0, 0, 1);    __syncthreads();   // q6: g3.h0
        STAGEPH(0, j0 + BN, 0, 0);  COMP1(1, 1, 1);    __syncthreads();   // q7: g3.h1 (+next tile; slack groups cover tail)

        // epilogue: e_m = n1_m - 2*dot (dot = acc/4096); min over versions; + n2; argmin
        float nn0 = n2[j0 + wn * 64 + c5];
        float nn1 = n2[j0 + wn * 64 + 32 + c5];
#pragma unroll
        for (int a = 0; a < 2; ++a)
#pragma unroll
            for (int b = 0; b < 2; ++b) {
                float nn = b ? nn1 : nn0;
                int j = j0 + wn * 64 + b * 32 + c5;
#pragma unroll
                for (int rq = 0; rq < 4; ++rq) {
                    float4 n1v = *(const float4*)&LDSn1[(wm * 2 + a) * 32 + 8 * rq + 4 * h];
                    float e0 = fmaf(-0.00048828125f, acc[a][b][4 * rq + 0], n1v.x);
                    float e1 = fmaf(-0.00048828125f, acc[a][b][4 * rq + 1], n1v.y);
                    float e2 = fmaf(-0.00048828125f, acc[a][b][4 * rq + 2], n1v.z);
                    float e3 = fmaf(-0.00048828125f, acc[a][b][4 * rq + 3], n1v.w);
                    float d = fminf(fminf(e0, e1), fminf(e2, e3)) + nn;
                    if (d < best[a][rq]) { best[a][rq] = d; bj[a][rq] = j; }
                }
            }
    }

    // reduce across the 32 column-lanes
#pragma unroll
    for (int off = 1; off < 32; off <<= 1) {
#pragma unroll
        for (int a = 0; a < 2; ++a)
#pragma unroll
            for (int rq = 0; rq < 4; ++rq) {
                float ov = __shfl_xor(best[a][rq], off);
                int oj = __shfl_xor(bj[a][rq], off);
                if (ov < best[a][rq] || (ov == best[a][rq] && oj < bj[a][rq])) {
                    best[a][rq] = ov; bj[a][rq] = oj;
                }
            }
    }
    if (c5 == 0) {
        int slot = ch * 2 + wn;
#pragma unroll
        for (int a = 0; a < 2; ++a)
#pragma unroll
            for (int rq = 0; rq < 4; ++rq) {
                int i = bi * 32 + (wm * 2 + a) * 8 + 2 * rq + h;
                pb[slot * B1P + i] = best[a][rq];
                pj[slot * B1P + i] = bj[a][rq];
            }
    }
}

__global__ void final_kernel(const float* __restrict__ pb, const int* __restrict__ pj,
                             float* __restrict__ out) {
    int i = blockIdx.x * 256 + threadIdx.x;
    if (i < NB1) {
        float bv = 3.4e38f;
        int bj = 0;
#pragma unroll
        for (int s = 0; s < 2 * NCHUNK; ++s) {
            float v = pb[s * B1P + i];
            int j = pj[s * B1P + i];
            if (v < bv || (v == bv && j < bj)) { bv = v; bj = j; }
        }
        out[i] = sqrtf(fmaxf(bv, 0.f));
        out[NB1 + 2 * i] = (float)i;
        out[NB1 + 2 * i + 1] = (float)bj;
    }
}

// ---------------- launch ----------------

extern "C" void kernel_launch(void* const* d_in, const int* in_sizes, int n_in,
                              void* d_out, int out_size, void* d_ws, size_t ws_size,
                              hipStream_t stream) {
    const float* desc1 = (const float*)d_in[0];
    const float* desc2 = (const float*)d_in[1];
    const float* G     = (const float*)d_in[2];

    unsigned short* A2c = (unsigned short*)d_ws;             // 1252*16*512 ushort
    unsigned short* B2c = A2c + (size_t)(B1R / 32) * 16 * 512;   // NB2G*16*512 ushort
    float* F0 = (float*)(B2c + (size_t)NB2G * 16 * 512);     // B1P*DD fp32 chain
    float* GT = F0 + (size_t)B1P * DD;                       // DD*DD
    float* n1 = GT + DD * DD;                                // B1R
    float* n2 = n1 + B1R;                                    // NB2P
    float* pb = n2 + NB2P;                                   // 2*NCHUNK*B1P
    int*   pj = (int*)(pb + 2 * NCHUNK * B1P);               // 2*NCHUNK*B1P
    float* out = (float*)d_out;

    hipLaunchKernelGGL(gt_kernel, dim3((DD * DD + 255) / 256), dim3(256), 0, stream, G, GT);
    hipLaunchKernelGGL(prep1_kernel, dim3(B1P), dim3(DD), 0, stream, desc1, A2c, F0, n1);
    hipLaunchKernelGGL(prep2_kernel, dim3(NB2P), dim3(DD), 0, stream, desc2, B2c, n2);
    for (int k = 1; k < NV; ++k)
        hipLaunchKernelGGL(steer_kernel, dim3(B1P / SROWS), dim3(DD), 0, stream,
                           F0, A2c, GT, n1, k);
    hipLaunchKernelGGL(match_kernel, dim3(B1R / MB, NCHUNK), dim3(256), 0, stream,
                       A2c, B2c, n1, n2, pb, pj);
    hipLaunchKernelGGL(final_kernel, dim3((NB1 + 255) / 256), dim3(256), 0, stream,
                       pb, pj, out);
}